// Round 5
// baseline (460.286 us; speedup 1.0000x reference)
//
#include <hip/hip_runtime.h>
#include <math.h>

#define BATCH 256
#define NPTS  16384
#define TPB   256

// pass1 tiling: grid (BATCH, P1_CHUNKS); 4 waves/block; wave handles 512 pts
#define P1_CHUNKS     8
#define P1_PTS_BLOCK  (NPTS / P1_CHUNKS)      // 2048
#define P1_ITERS      8                        // 8 iters x 64 pts = 512 pts/wave

// ---- workspace: per-(batch,chunk) partials, stride 256 floats ----
// [0..63] chMax, [64..127] chSum, [128..191] chSumSq, [192..200] moments
#define PART_STRIDE 256
#define COUNTER_OFF (BATCH * P1_CHUNKS * PART_STRIDE)   // word offset of counters

typedef __bf16 bf16x8  __attribute__((ext_vector_type(8)));
typedef float  floatx4 __attribute__((ext_vector_type(4)));

// ---------------- init: zero per-batch arrival counters ----------------
__global__ void init_counters_kernel(unsigned* __restrict__ wsu) {
    wsu[COUNTER_OFF + threadIdx.x] = 0u;
}

// ---------------- fused: pass1 + (last block per batch) mid phase ----------------
// A-frag (16x16x32 bf16): A[m = lane&15][k = (lane>>4)*8 + j]
// B-frag:                 B[k = (lane>>4)*8 + j][n = lane&15]
// C/D layout:             col = lane&15, row = (lane>>4)*4 + reg   [m89]
// NOTE: scalar accumulators (vmax/vsum/vsq[4]) are load-bearing: this kernel
// sits at the 64-VGPR cliff; the R3 packed-vector variant spilled to scratch
// (747 MB WRITE_SIZE, 6x regression). Do not grow hot-loop live state.
__global__ __launch_bounds__(TPB, 4)
void fused_kernel(const float* __restrict__ x, const float* __restrict__ W1,
                  const float* __restrict__ b1, const float* __restrict__ W2,
                  const float* __restrict__ b2,
                  const float* __restrict__ W3, const float* __restrict__ b3,
                  const float* __restrict__ W4, const float* __restrict__ b4,
                  const float* __restrict__ W5, const float* __restrict__ b5,
                  float* __restrict__ ws, float* __restrict__ out) {
    const int b     = blockIdx.x;
    const int chunk = blockIdx.y;
    const int tid   = threadIdx.x;
    const int lane  = tid & 63;
    const int wave  = tid >> 6;
    const int quad  = lane >> 4;
    const int l15   = lane & 15;

    // W2 (32x64) as 4 B-frags (16-channel tiles); bias per (tile, l15)
    bf16x8 Bf[4];
    float  b2n[4];
#pragma unroll
    for (int t = 0; t < 4; ++t) {
        int n = t * 16 + l15;
#pragma unroll
        for (int j = 0; j < 8; ++j)
            Bf[t][j] = (__bf16)W2[(quad * 8 + j) * 64 + n];
        b2n[t] = b2[n];
    }
    // layer-1 weights for this lane's k-range (k = quad*8 + j)
    float w1a[8], w1b[8], b1r[8];
#pragma unroll
    for (int j = 0; j < 8; ++j) {
        int jj = quad * 8 + j;
        w1a[j] = W1[jj];
        w1b[j] = W1[32 + jj];
        b1r[j] = b1[jj];
    }

    float vmax[4] = {0.f, 0.f, 0.f, 0.f};
    float vsum[4] = {0.f, 0.f, 0.f, 0.f};
    float vsq[4]  = {0.f, 0.f, 0.f, 0.f};
    float mo[9];
#pragma unroll
    for (int j = 0; j < 9; ++j) mo[j] = 0.f;

    const float* xb = x + ((size_t)b * NPTS + (size_t)chunk * P1_PTS_BLOCK) * 5;

    for (int it = 0; it < P1_ITERS; ++it) {
        const int pbase = wave * (P1_ITERS * 64) + it * 64;
        const float* p = xb + (size_t)(pbase + lane) * 5;
        float c0 = p[0], c1 = p[1], c2 = p[2], s0 = p[3], s1 = p[4];
        mo[0] += c0; mo[1] += c1; mo[2] += c2;
        mo[3] = fmaf(c0, c0, mo[3]); mo[4] = fmaf(c0, c1, mo[4]); mo[5] = fmaf(c0, c2, mo[5]);
        mo[6] = fmaf(c1, c1, mo[6]); mo[7] = fmaf(c1, c2, mo[7]); mo[8] = fmaf(c2, c2, mo[8]);

#pragma unroll
        for (int g = 0; g < 4; ++g) {
            int src = g * 16 + l15;
            float gs0 = __shfl(s0, src);
            float gs1 = __shfl(s1, src);
            bf16x8 Af;
#pragma unroll
            for (int j = 0; j < 8; ++j) {
                float v = fmaf(gs0, w1a[j], fmaf(gs1, w1b[j], b1r[j]));
                Af[j] = (__bf16)fmaxf(v, 0.f);
            }
#pragma unroll
            for (int t = 0; t < 4; ++t) {
                floatx4 C = {b2n[t], b2n[t], b2n[t], b2n[t]};   // bias folded into C
                C = __builtin_amdgcn_mfma_f32_16x16x32_bf16(Af, Bf[t], C, 0, 0, 0);
#pragma unroll
                for (int r = 0; r < 4; ++r) {
                    float v = fmaxf(C[r], 0.f);
                    vmax[t] = fmaxf(vmax[t], v);
                    vsum[t] += v;
                    vsq[t]  = fmaf(v, v, vsq[t]);
                }
            }
        }
    }

    // combine quads (lanes sharing l15)
#pragma unroll
    for (int t = 0; t < 4; ++t) {
        vmax[t] = fmaxf(vmax[t], __shfl_xor(vmax[t], 16));
        vmax[t] = fmaxf(vmax[t], __shfl_xor(vmax[t], 32));
        vsum[t] += __shfl_xor(vsum[t], 16);
        vsum[t] += __shfl_xor(vsum[t], 32);
        vsq[t]  += __shfl_xor(vsq[t], 16);
        vsq[t]  += __shfl_xor(vsq[t], 32);
    }
#pragma unroll
    for (int j = 0; j < 9; ++j) {
        float v = mo[j];
#pragma unroll
        for (int o = 32; o > 0; o >>= 1) v += __shfl_xor(v, o);
        mo[j] = v;
    }

    __shared__ float red[4][201];
    if (quad == 0) {
#pragma unroll
        for (int t = 0; t < 4; ++t) {
            red[wave][t * 16 + l15]       = vmax[t];
            red[wave][64 + t * 16 + l15]  = vsum[t];
            red[wave][128 + t * 16 + l15] = vsq[t];
        }
    }
    if (lane == 0) {
#pragma unroll
        for (int j = 0; j < 9; ++j) red[wave][192 + j] = mo[j];
    }
    __syncthreads();

    // non-atomic partial write: slot (b*P1_CHUNKS + chunk)
    if (tid < 201) {
        float v0 = red[0][tid], v1 = red[1][tid], v2 = red[2][tid], v3 = red[3][tid];
        float r = (tid < 64) ? fmaxf(fmaxf(v0, v1), fmaxf(v2, v3))
                             : (v0 + v1) + (v2 + v3);
        ws[(size_t)(b * P1_CHUNKS + chunk) * PART_STRIDE + tid] = r;
    }

    // --- last-block-per-batch election (release: fence before atomic) ---
    __threadfence();
    __syncthreads();
    __shared__ unsigned arrival;
    if (tid == 0) {
        unsigned* cnt = (unsigned*)ws + COUNTER_OFF + b;
        arrival = atomicAdd(cnt, 1u);
    }
    __syncthreads();
    if (arrival != P1_CHUNKS - 1) return;   // not the last block of this batch
    __threadfence();                        // acquire side

    // ================= mid phase (winner block only) =================
    const int lane2 = tid & 63, wave2 = tid >> 6;
    __shared__ float comb[201];
    __shared__ float eg[15];        // [0..8] evecs, [9..11] eig_norm, [12..14] centroid
    __shared__ float redmm[4][8];
    __shared__ float g[224];
    __shared__ float h1[256];
    __shared__ float h2[128];

    // reduce the 8 per-chunk partials (volatile: bypass any stale L1 lines)
    if (tid < 201) {
        volatile const float* base = ws + (size_t)b * P1_CHUNKS * PART_STRIDE + tid;
        float acc = base[0];
        if (tid < 64) {
#pragma unroll
            for (int i = 1; i < P1_CHUNKS; ++i) acc = fmaxf(acc, base[i * PART_STRIDE]);
        } else {
#pragma unroll
            for (int i = 1; i < P1_CHUNKS; ++i) acc += base[i * PART_STRIDE];
        }
        comb[tid] = acc;
    }
    __syncthreads();

    // fp32 Jacobi eigh (thread 0)
    if (tid == 0) {
        const float n = (float)NPTS;
        float mx = comb[192] / n, my = comb[193] / n, mz = comb[194] / n;
        float A[3][3];
        A[0][0] = comb[195] / n - mx * mx; A[0][1] = comb[196] / n - mx * my;
        A[0][2] = comb[197] / n - mx * mz;
        A[1][1] = comb[198] / n - my * my; A[1][2] = comb[199] / n - my * mz;
        A[2][2] = comb[200] / n - mz * mz;
        A[1][0] = A[0][1]; A[2][0] = A[0][2]; A[2][1] = A[1][2];
        float V[3][3] = {{1, 0, 0}, {0, 1, 0}, {0, 0, 1}};
        const int PP[3] = {0, 0, 1};
        const int QQ[3] = {1, 2, 2};
        for (int sweep = 0; sweep < 7; ++sweep) {
            for (int r3 = 0; r3 < 3; ++r3) {
                int p = PP[r3], q = QQ[r3];
                float apq = A[p][q];
                if (fabsf(apq) < 1e-35f) continue;
                float theta = (A[q][q] - A[p][p]) / (2.0f * apq);
                float tt = 1.0f / (fabsf(theta) + sqrtf(fmaf(theta, theta, 1.0f)));
                if (theta < 0.0f) tt = -tt;
                float c = 1.0f / sqrtf(fmaf(tt, tt, 1.0f)), s = tt * c;
                float apq_t = tt * apq;
                A[p][p] -= apq_t;
                A[q][q] += apq_t;
                A[p][q] = A[q][p] = 0.0f;
                for (int r = 0; r < 3; ++r) {
                    if (r != p && r != q) {
                        float arp = A[r][p], arq = A[r][q];
                        A[r][p] = A[p][r] = c * arp - s * arq;
                        A[r][q] = A[q][r] = s * arp + c * arq;
                    }
                    float vrp = V[r][p], vrq = V[r][q];
                    V[r][p] = c * vrp - s * vrq;
                    V[r][q] = s * vrp + c * vrq;
                }
            }
        }
        float w[3] = {A[0][0], A[1][1], A[2][2]};
        int i0 = 0, i1 = 1, i2 = 2, sw;
        if (w[i0] < w[i1]) { sw = i0; i0 = i1; i1 = sw; }
        if (w[i0] < w[i2]) { sw = i0; i0 = i2; i2 = sw; }
        if (w[i1] < w[i2]) { sw = i1; i1 = i2; i2 = sw; }
        int idx[3] = {i0, i1, i2};
        for (int e = 0; e < 3; ++e)
            for (int comp = 0; comp < 3; ++comp)
                eg[e * 3 + comp] = V[comp][idx[e]];
        float sum = w[0] + w[1] + w[2] + 1e-8f;
        for (int e = 0; e < 3; ++e) eg[9 + e] = w[idx[e]] / sum;
        eg[12] = mx; eg[13] = my; eg[14] = mz;
    }
    __syncthreads();

    // projection extents over this batch's 16384 points
    float e0x = eg[0], e0y = eg[1], e0z = eg[2];
    float e1x = eg[3], e1y = eg[4], e1z = eg[5];
    float e2x = eg[6], e2y = eg[7], e2z = eg[8];
    float cx = eg[12], cy = eg[13], cz = eg[14];

    const float* xf = x + (size_t)b * NPTS * 5;
    float mn[3] = {3.4e38f, 3.4e38f, 3.4e38f};
    float mx3[3] = {-3.4e38f, -3.4e38f, -3.4e38f};
#pragma unroll 4
    for (int i = 0; i < NPTS / TPB; ++i) {
        const float* p = xf + (size_t)(i * TPB + tid) * 5;
        float c0 = p[0] - cx, c1 = p[1] - cy, c2 = p[2] - cz;
        float p0 = fmaf(c0, e0x, fmaf(c1, e0y, c2 * e0z));
        float p1 = fmaf(c0, e1x, fmaf(c1, e1y, c2 * e1z));
        float p2 = fmaf(c0, e2x, fmaf(c1, e2y, c2 * e2z));
        mn[0] = fminf(mn[0], p0); mx3[0] = fmaxf(mx3[0], p0);
        mn[1] = fminf(mn[1], p1); mx3[1] = fmaxf(mx3[1], p1);
        mn[2] = fminf(mn[2], p2); mx3[2] = fmaxf(mx3[2], p2);
    }
#pragma unroll
    for (int d = 0; d < 3; ++d) {
        float v = mx3[d];
#pragma unroll
        for (int o = 32; o > 0; o >>= 1) v = fmaxf(v, __shfl_xor(v, o));
        if (lane2 == 0) redmm[wave2][d] = v;
        float u = mn[d];
#pragma unroll
        for (int o = 32; o > 0; o >>= 1) u = fminf(u, __shfl_xor(u, o));
        if (lane2 == 0) redmm[wave2][4 + d] = u;
    }
    __syncthreads();

    // assemble g(201)
    if (tid < 64) {
        g[tid] = comb[tid];
        float s = comb[64 + tid], sq = comb[128 + tid];
        float avg = s * (1.0f / NPTS);
        g[64 + tid] = avg;
        float var = (sq - s * avg) / (float)(NPTS - 1);
        g[128 + tid] = sqrtf(fmaxf(var, 0.f));
    } else if (tid < 73) {
        int j = tid - 64;
        if (j < 3) {
            g[192 + j] = eg[9 + j];
        } else if (j < 6) {
            int d = j - 3;
            float fmx = fmaxf(fmaxf(redmm[0][d], redmm[1][d]), fmaxf(redmm[2][d], redmm[3][d]));
            float fmn = fminf(fminf(redmm[0][4 + d], redmm[1][4 + d]),
                              fminf(redmm[2][4 + d], redmm[3][4 + d]));
            g[195 + d] = fmx - fmn;
        } else {
            g[198 + (j - 6)] = eg[12 + (j - 6)];
        }
    }
    __syncthreads();

    // final MLP 201 -> 256 -> 128 -> 256
    float a = b3[tid];
    for (int j = 0; j < 201; ++j) a = fmaf(g[j], W3[j * 256 + tid], a);
    h1[tid] = fmaxf(a, 0.f);
    __syncthreads();
    if (tid < 128) {
        float a2 = b4[tid];
        for (int j = 0; j < 256; ++j) a2 = fmaf(h1[j], W4[j * 128 + tid], a2);
        h2[tid] = fmaxf(a2, 0.f);
    }
    __syncthreads();
    float o = b5[tid];
    for (int j = 0; j < 128; ++j) o = fmaf(h2[j], W5[j * 256 + tid], o);
    out[(size_t)b * 256 + tid] = o;
}

extern "C" void kernel_launch(void* const* d_in, const int* in_sizes, int n_in,
                              void* d_out, int out_size, void* d_ws, size_t ws_size,
                              hipStream_t stream) {
    const float* x  = (const float*)d_in[0];
    const float* W1 = (const float*)d_in[1];
    const float* b1 = (const float*)d_in[2];
    const float* W2 = (const float*)d_in[3];
    const float* b2 = (const float*)d_in[4];
    const float* W3 = (const float*)d_in[5];
    const float* b3 = (const float*)d_in[6];
    const float* W4 = (const float*)d_in[7];
    const float* b4 = (const float*)d_in[8];
    const float* W5 = (const float*)d_in[9];
    const float* b5 = (const float*)d_in[10];
    float* out = (float*)d_out;
    float* ws  = (float*)d_ws;

    init_counters_kernel<<<dim3(1), BATCH, 0, stream>>>((unsigned*)ws);
    fused_kernel<<<dim3(BATCH, P1_CHUNKS), TPB, 0, stream>>>(
        x, W1, b1, W2, b2, W3, b3, W4, b4, W5, b5, ws, out);
}

// Round 6
// 206.868 us; speedup vs baseline: 2.2250x; 2.2250x over previous
//
#include <hip/hip_runtime.h>
#include <math.h>

#define BATCH 256
#define NPTS  16384
#define TPB   256
#define MID_TPB 1024

// pass1 tiling: grid (BATCH, P1_CHUNKS); 4 waves/block; wave handles 512 pts
#define P1_CHUNKS     8
#define P1_PTS_BLOCK  (NPTS / P1_CHUNKS)      // 2048
#define P1_ITERS      8                        // 8 iters x 64 pts = 512 pts/wave

// ---- workspace: per-(batch,chunk) partials, stride 256 floats ----
// [0..63] chMax, [64..127] chSum, [128..191] chSumSq, [192..200] moments
#define PART_STRIDE 256

typedef __bf16 bf16x8  __attribute__((ext_vector_type(8)));
typedef float  floatx4 __attribute__((ext_vector_type(4)));

// ---------------- pass 1: coord moments + MFMA point-MLP + channel stats ----------------
// A-frag (16x16x32 bf16): A[m = lane&15][k = (lane>>4)*8 + j]
// B-frag:                 B[k = (lane>>4)*8 + j][n = lane&15]
// C/D layout:             col = lane&15, row = (lane>>4)*4 + reg   [m89]
// NOTE: scalar accumulators (vmax/vsum/vsq[4]) are load-bearing: this kernel
// sits at the 64-VGPR cliff; the R3 packed-vector variant spilled to scratch
// (747 MB WRITE_SIZE, 6x regression). Do not grow hot-loop live state.
// NOTE2 (R5): do NOT fuse the mid phase in via per-block __threadfence()
// election — device-scope fences are L2 writeback/invalidate ops on gfx950
// and serialized the whole dispatch (63 -> 357 us).
__global__ __launch_bounds__(TPB, 4)
void pass1_kernel(const float* __restrict__ x, const float* __restrict__ W1,
                  const float* __restrict__ b1, const float* __restrict__ W2,
                  const float* __restrict__ b2, float* __restrict__ ws) {
    const int b     = blockIdx.x;
    const int chunk = blockIdx.y;
    const int tid   = threadIdx.x;
    const int lane  = tid & 63;
    const int wave  = tid >> 6;
    const int quad  = lane >> 4;
    const int l15   = lane & 15;

    // W2 (32x64) as 4 B-frags (16-channel tiles); bias per (tile, l15)
    bf16x8 Bf[4];
    float  b2n[4];
#pragma unroll
    for (int t = 0; t < 4; ++t) {
        int n = t * 16 + l15;
#pragma unroll
        for (int j = 0; j < 8; ++j)
            Bf[t][j] = (__bf16)W2[(quad * 8 + j) * 64 + n];
        b2n[t] = b2[n];
    }
    // layer-1 weights for this lane's k-range (k = quad*8 + j)
    float w1a[8], w1b[8], b1r[8];
#pragma unroll
    for (int j = 0; j < 8; ++j) {
        int jj = quad * 8 + j;
        w1a[j] = W1[jj];
        w1b[j] = W1[32 + jj];
        b1r[j] = b1[jj];
    }

    float vmax[4] = {0.f, 0.f, 0.f, 0.f};
    float vsum[4] = {0.f, 0.f, 0.f, 0.f};
    float vsq[4]  = {0.f, 0.f, 0.f, 0.f};
    float mo[9];
#pragma unroll
    for (int j = 0; j < 9; ++j) mo[j] = 0.f;

    const float* xb = x + ((size_t)b * NPTS + (size_t)chunk * P1_PTS_BLOCK) * 5;

    for (int it = 0; it < P1_ITERS; ++it) {
        const int pbase = wave * (P1_ITERS * 64) + it * 64;
        const float* p = xb + (size_t)(pbase + lane) * 5;
        float c0 = p[0], c1 = p[1], c2 = p[2], s0 = p[3], s1 = p[4];
        mo[0] += c0; mo[1] += c1; mo[2] += c2;
        mo[3] = fmaf(c0, c0, mo[3]); mo[4] = fmaf(c0, c1, mo[4]); mo[5] = fmaf(c0, c2, mo[5]);
        mo[6] = fmaf(c1, c1, mo[6]); mo[7] = fmaf(c1, c2, mo[7]); mo[8] = fmaf(c2, c2, mo[8]);

#pragma unroll
        for (int g = 0; g < 4; ++g) {
            int src = g * 16 + l15;
            float gs0 = __shfl(s0, src);
            float gs1 = __shfl(s1, src);
            bf16x8 Af;
#pragma unroll
            for (int j = 0; j < 8; ++j) {
                float v = fmaf(gs0, w1a[j], fmaf(gs1, w1b[j], b1r[j]));
                Af[j] = (__bf16)fmaxf(v, 0.f);
            }
#pragma unroll
            for (int t = 0; t < 4; ++t) {
                floatx4 C = {b2n[t], b2n[t], b2n[t], b2n[t]};   // bias folded into C
                C = __builtin_amdgcn_mfma_f32_16x16x32_bf16(Af, Bf[t], C, 0, 0, 0);
#pragma unroll
                for (int r = 0; r < 4; ++r) {
                    float v = fmaxf(C[r], 0.f);
                    vmax[t] = fmaxf(vmax[t], v);
                    vsum[t] += v;
                    vsq[t]  = fmaf(v, v, vsq[t]);
                }
            }
        }
    }

    // combine quads (lanes sharing l15)
#pragma unroll
    for (int t = 0; t < 4; ++t) {
        vmax[t] = fmaxf(vmax[t], __shfl_xor(vmax[t], 16));
        vmax[t] = fmaxf(vmax[t], __shfl_xor(vmax[t], 32));
        vsum[t] += __shfl_xor(vsum[t], 16);
        vsum[t] += __shfl_xor(vsum[t], 32);
        vsq[t]  += __shfl_xor(vsq[t], 16);
        vsq[t]  += __shfl_xor(vsq[t], 32);
    }
#pragma unroll
    for (int j = 0; j < 9; ++j) {
        float v = mo[j];
#pragma unroll
        for (int o = 32; o > 0; o >>= 1) v += __shfl_xor(v, o);
        mo[j] = v;
    }

    __shared__ float red[4][201];
    if (quad == 0) {
#pragma unroll
        for (int t = 0; t < 4; ++t) {
            red[wave][t * 16 + l15]       = vmax[t];
            red[wave][64 + t * 16 + l15]  = vsum[t];
            red[wave][128 + t * 16 + l15] = vsq[t];
        }
    }
    if (lane == 0) {
#pragma unroll
        for (int j = 0; j < 9; ++j) red[wave][192 + j] = mo[j];
    }
    __syncthreads();

    // non-atomic partial write: slot (b*P1_CHUNKS + chunk)
    if (tid < 201) {
        float v0 = red[0][tid], v1 = red[1][tid], v2 = red[2][tid], v3 = red[3][tid];
        float r = (tid < 64) ? fmaxf(fmaxf(v0, v1), fmaxf(v2, v3))
                             : (v0 + v1) + (v2 + v3);
        ws[(size_t)(b * P1_CHUNKS + chunk) * PART_STRIDE + tid] = r;
    }
}

// ---------------- fused mid: reduce partials + eigh + extents + final MLP ----------------
// 1024 threads: 16 waves for the latency-bound extents scan; MLP layers use
// split-K partial sums across the extra waves.
__global__ __launch_bounds__(MID_TPB)
void mid_kernel(const float* __restrict__ x,
                const float* __restrict__ W3, const float* __restrict__ b3,
                const float* __restrict__ W4, const float* __restrict__ b4,
                const float* __restrict__ W5, const float* __restrict__ b5,
                const float* __restrict__ ws, float* __restrict__ out) {
    const int b = blockIdx.x, t = threadIdx.x;
    const int lane = t & 63, wave = t >> 6;

    __shared__ float comb[201];
    __shared__ float eg[15];        // [0..8] evecs, [9..11] eig_norm, [12..14] centroid
    __shared__ float redmm[16][8];
    __shared__ float g[224];
    __shared__ float h1[256];
    __shared__ float h2[128];
    __shared__ float part[8][256];  // split-K partial sums

    // --- reduce the 8 per-chunk partials ---
    if (t < 201) {
        const float* base = ws + (size_t)b * P1_CHUNKS * PART_STRIDE + t;
        float acc = base[0];
        if (t < 64) {
#pragma unroll
            for (int i = 1; i < P1_CHUNKS; ++i) acc = fmaxf(acc, base[i * PART_STRIDE]);
        } else {
#pragma unroll
            for (int i = 1; i < P1_CHUNKS; ++i) acc += base[i * PART_STRIDE];
        }
        comb[t] = acc;
    }
    __syncthreads();

    // --- fp32 Jacobi eigh (thread 0) ---
    if (t == 0) {
        const float n = (float)NPTS;
        float mx = comb[192] / n, my = comb[193] / n, mz = comb[194] / n;
        float A[3][3];
        A[0][0] = comb[195] / n - mx * mx; A[0][1] = comb[196] / n - mx * my;
        A[0][2] = comb[197] / n - mx * mz;
        A[1][1] = comb[198] / n - my * my; A[1][2] = comb[199] / n - my * mz;
        A[2][2] = comb[200] / n - mz * mz;
        A[1][0] = A[0][1]; A[2][0] = A[0][2]; A[2][1] = A[1][2];
        float V[3][3] = {{1, 0, 0}, {0, 1, 0}, {0, 0, 1}};
        const int PP[3] = {0, 0, 1};
        const int QQ[3] = {1, 2, 2};
        for (int sweep = 0; sweep < 7; ++sweep) {
            for (int r3 = 0; r3 < 3; ++r3) {
                int p = PP[r3], q = QQ[r3];
                float apq = A[p][q];
                if (fabsf(apq) < 1e-35f) continue;
                float theta = (A[q][q] - A[p][p]) / (2.0f * apq);
                float tt = 1.0f / (fabsf(theta) + sqrtf(fmaf(theta, theta, 1.0f)));
                if (theta < 0.0f) tt = -tt;
                float c = 1.0f / sqrtf(fmaf(tt, tt, 1.0f)), s = tt * c;
                float apq_t = tt * apq;
                A[p][p] -= apq_t;
                A[q][q] += apq_t;
                A[p][q] = A[q][p] = 0.0f;
                for (int r = 0; r < 3; ++r) {
                    if (r != p && r != q) {
                        float arp = A[r][p], arq = A[r][q];
                        A[r][p] = A[p][r] = c * arp - s * arq;
                        A[r][q] = A[q][r] = s * arp + c * arq;
                    }
                    float vrp = V[r][p], vrq = V[r][q];
                    V[r][p] = c * vrp - s * vrq;
                    V[r][q] = s * vrp + c * vrq;
                }
            }
        }
        float w[3] = {A[0][0], A[1][1], A[2][2]};
        int i0 = 0, i1 = 1, i2 = 2, sw;
        if (w[i0] < w[i1]) { sw = i0; i0 = i1; i1 = sw; }
        if (w[i0] < w[i2]) { sw = i0; i0 = i2; i2 = sw; }
        if (w[i1] < w[i2]) { sw = i1; i1 = i2; i2 = sw; }
        int idx[3] = {i0, i1, i2};
        for (int e = 0; e < 3; ++e)
            for (int comp = 0; comp < 3; ++comp)
                eg[e * 3 + comp] = V[comp][idx[e]];
        float sum = w[0] + w[1] + w[2] + 1e-8f;
        for (int e = 0; e < 3; ++e) eg[9 + e] = w[idx[e]] / sum;
        eg[12] = mx; eg[13] = my; eg[14] = mz;
    }
    __syncthreads();

    // --- projection extents over this batch's 16384 points (16 waves) ---
    float e0x = eg[0], e0y = eg[1], e0z = eg[2];
    float e1x = eg[3], e1y = eg[4], e1z = eg[5];
    float e2x = eg[6], e2y = eg[7], e2z = eg[8];
    float cx = eg[12], cy = eg[13], cz = eg[14];

    const float* xb = x + (size_t)b * NPTS * 5;
    float mn[3] = {3.4e38f, 3.4e38f, 3.4e38f};
    float mx3[3] = {-3.4e38f, -3.4e38f, -3.4e38f};
#pragma unroll 4
    for (int i = 0; i < NPTS / MID_TPB; ++i) {
        const float* p = xb + (size_t)(i * MID_TPB + t) * 5;
        float c0 = p[0] - cx, c1 = p[1] - cy, c2 = p[2] - cz;
        float p0 = fmaf(c0, e0x, fmaf(c1, e0y, c2 * e0z));
        float p1 = fmaf(c0, e1x, fmaf(c1, e1y, c2 * e1z));
        float p2 = fmaf(c0, e2x, fmaf(c1, e2y, c2 * e2z));
        mn[0] = fminf(mn[0], p0); mx3[0] = fmaxf(mx3[0], p0);
        mn[1] = fminf(mn[1], p1); mx3[1] = fmaxf(mx3[1], p1);
        mn[2] = fminf(mn[2], p2); mx3[2] = fmaxf(mx3[2], p2);
    }
#pragma unroll
    for (int d = 0; d < 3; ++d) {
        float v = mx3[d];
#pragma unroll
        for (int o = 32; o > 0; o >>= 1) v = fmaxf(v, __shfl_xor(v, o));
        if (lane == 0) redmm[wave][d] = v;
        float u = mn[d];
#pragma unroll
        for (int o = 32; o > 0; o >>= 1) u = fminf(u, __shfl_xor(u, o));
        if (lane == 0) redmm[wave][4 + d] = u;
    }
    __syncthreads();

    // --- assemble g(201) ---
    if (t < 64) {
        g[t] = comb[t];
        float s = comb[64 + t], sq = comb[128 + t];
        float avg = s * (1.0f / NPTS);
        g[64 + t] = avg;
        float var = (sq - s * avg) / (float)(NPTS - 1);
        g[128 + t] = sqrtf(fmaxf(var, 0.f));
    } else if (t < 73) {
        int j = t - 64;
        if (j < 3) {
            g[192 + j] = eg[9 + j];
        } else if (j < 6) {
            int d = j - 3;
            float fmx = redmm[0][d], fmn = redmm[0][4 + d];
#pragma unroll
            for (int w2 = 1; w2 < 16; ++w2) {
                fmx = fmaxf(fmx, redmm[w2][d]);
                fmn = fminf(fmn, redmm[w2][4 + d]);
            }
            g[195 + d] = fmx - fmn;
        } else {
            g[198 + (j - 6)] = eg[12 + (j - 6)];
        }
    }
    __syncthreads();

    // --- final MLP 201 -> 256 -> 128 -> 256, split-K over waves ---
    // layer 1: 4 slices of ~51 over j in [0,201)
    {
        int p = t >> 8, c = t & 255;
        int j0 = p * 51, j1 = min(201, j0 + 51);
        float a = 0.f;
        for (int j = j0; j < j1; ++j) a = fmaf(g[j], W3[j * 256 + c], a);
        part[p][c] = a;
    }
    __syncthreads();
    if (t < 256) {
        float a = b3[t] + (part[0][t] + part[1][t]) + (part[2][t] + part[3][t]);
        h1[t] = fmaxf(a, 0.f);
    }
    __syncthreads();
    // layer 2: 8 slices of 32 over j in [0,256)
    {
        int p = t >> 7, c = t & 127;
        int j0 = p * 32;
        float a = 0.f;
#pragma unroll
        for (int j = j0; j < j0 + 32; ++j) a = fmaf(h1[j], W4[j * 128 + c], a);
        part[p][c] = a;
    }
    __syncthreads();
    if (t < 128) {
        float a = b4[t];
#pragma unroll
        for (int p = 0; p < 8; ++p) a += part[p][t];
        h2[t] = fmaxf(a, 0.f);
    }
    __syncthreads();
    // layer 3: 4 slices of 32 over j in [0,128)
    {
        int p = t >> 8, c = t & 255;
        int j0 = p * 32;
        float a = 0.f;
#pragma unroll
        for (int j = j0; j < j0 + 32; ++j) a = fmaf(h2[j], W5[j * 256 + c], a);
        part[p][c] = a;
    }
    __syncthreads();
    if (t < 256) {
        float o = b5[t] + (part[0][t] + part[1][t]) + (part[2][t] + part[3][t]);
        out[(size_t)b * 256 + t] = o;
    }
}

extern "C" void kernel_launch(void* const* d_in, const int* in_sizes, int n_in,
                              void* d_out, int out_size, void* d_ws, size_t ws_size,
                              hipStream_t stream) {
    const float* x  = (const float*)d_in[0];
    const float* W1 = (const float*)d_in[1];
    const float* b1 = (const float*)d_in[2];
    const float* W2 = (const float*)d_in[3];
    const float* b2 = (const float*)d_in[4];
    const float* W3 = (const float*)d_in[5];
    const float* b3 = (const float*)d_in[6];
    const float* W4 = (const float*)d_in[7];
    const float* b4 = (const float*)d_in[8];
    const float* W5 = (const float*)d_in[9];
    const float* b5 = (const float*)d_in[10];
    float* out = (float*)d_out;
    float* ws  = (float*)d_ws;

    pass1_kernel<<<dim3(BATCH, P1_CHUNKS), TPB, 0, stream>>>(x, W1, b1, W2, b2, ws);
    mid_kernel<<<dim3(BATCH), MID_TPB, 0, stream>>>(x, W3, b3, W4, b4, W5, b5, ws, out);
}